// Round 23
// baseline (172.452 us; speedup 1.0000x reference)
//
#include <hip/hip_runtime.h>

#define EPS 1e-10f
#define HALF_LN2PI 0.91893853320467274f
#define LOG2E 1.4426950408889634f

// b=16, win=14, w=6, ww=36, B_T=32, K=3, Bkk=288 (=i), C_T=32, HH=16
// W flat: [i=288][c=32][hr=4][m=4]
// Pt per (bb,p) (natural layout): Pt[i*16 + e] = patchflat[base(p)+e],
//   e = m*4+hc, base(p)=(p/6)*96+(p%6)*16.
//
// Grid (m/e) r23: 4608 blocks = (blk = bb*36+p)*8 + iq8, 128 threads = 2 waves.
// Block owns 36 i (i0 = iq8*36), wave owns 18. 16 blocks/CU = 32 waves/CU
// (FULL wave-slot cap; was 27/32 at 3-wave blocks). Grid 4608 vs 4096
// resident -> fine-grained drain (~12%), modeled net +5%.
// lane = cl*4+hr; thread covers c in {cl, cl+16}, 4 hc each.
// Mpart[bid][k*64+lane] (bid = blk*8+iq8), k: [0..3]=S1a [4..7]=S2a
// [8..11]=S1b [12..15]=S2b [16]=sRa [17]=sRb.
// f_pass reduces the 8 iq partials and writes PER-LANE packed Horner coeffs
// IN PLACE over Mpart[blk*9216 + {A2:q*256+lane*4+hc, A1:+512, A0:+1024,
// a:1536+q*16+cl}] (r22-validated; per-lane keeps the hr dimension).
//
// Structure: m0 -> f0 -> e0 -> m1 -> f1 -> e1 -> m2 -> f<FINAL> (8 dispatches).
//
// Post-mortems: r6 coop grid.sync; r7 full-unroll spill; r8 no global VMEM in
// t-loops; r9 DPP reduce, no memset; r11/r12 output path FREE; r13 preamble
// real; r14/r15/r20 t-loop instr cuts null; r16 occupancy 18->27 waves +7us;
// r17/r18 packed FP32 (kept; VALU -16pt); r19 poly-exp HURT; r21 hr-bug;
// r22 per-lane hoist +7us. r23 (this): occupancy 27->32 waves/CU.

typedef float f32x2 __attribute__((ext_vector_type(2)));

__device__ __forceinline__ f32x2 fma2(f32x2 a, f32x2 b, f32x2 c) {
    return __builtin_elementwise_fma(a, b, c);
}
__device__ __forceinline__ f32x2 sp2(float x) { return f32x2{x, x}; }

__device__ __forceinline__ void dot_pairs(const float4 wv,
                                          const float4 q0, const float4 q1,
                                          const float4 q2, const float4 q3,
                                          f32x2& out01, f32x2& out23)
{
    out01 = fma2(sp2(wv.x), f32x2{q0.x, q0.y},
            fma2(sp2(wv.y), f32x2{q1.x, q1.y},
            fma2(sp2(wv.z), f32x2{q2.x, q2.y}, sp2(wv.w) * f32x2{q3.x, q3.y})));
    out23 = fma2(sp2(wv.x), f32x2{q0.z, q0.w},
            fma2(sp2(wv.y), f32x2{q1.z, q1.w},
            fma2(sp2(wv.z), f32x2{q2.z, q2.w}, sp2(wv.w) * f32x2{q3.z, q3.w})));
}

__device__ __forceinline__ float qxor1_add(float x) {
    float r;
    asm("v_add_f32 %0, %1, %1 quad_perm:[1,0,3,2] row_mask:0xf bank_mask:0xf"
        : "=v"(r) : "v"(x));
    return r;
}
__device__ __forceinline__ float qxor2_add(float x) {
    float r;
    asm("v_add_f32 %0, %1, %1 quad_perm:[2,3,0,1] row_mask:0xf bank_mask:0xf"
        : "=v"(r) : "v"(x));
    return r;
}

template <int IT>
__global__ __launch_bounds__(128)
void m_pass(const float* __restrict__ poses, const float* __restrict__ acts,
            float* __restrict__ Ptg, float* __restrict__ actp,
            const float* __restrict__ W,
            const float* __restrict__ ap_buf, const float* __restrict__ denom_prev,
            float* __restrict__ Mpart, float* __restrict__ denom_zero)
{
    __shared__ __align__(16) float Pt_lds[576];    // 36 i x 16
    __shared__ float act_lds[36];
    __shared__ float invd_lds[36];
    __shared__ __align__(16) float red[1152];      // 1 donor wave x 64 x 18

    const int tid  = threadIdx.x;
    const int wave = tid >> 6, lane = tid & 63;
    const int cl   = lane >> 2;
    const int bid  = blockIdx.x;
    const int blk  = bid >> 3, iq = bid & 7;
    const int bb   = blk / 36, p = blk - bb * 36;
    const int i0   = iq * 36;
    const int iw   = i0 + wave * 18;
    const size_t pbase  = (size_t)blk * 4608;
    const size_t apbase = (size_t)blk * 9216;

    if (tid < 36)
        denom_zero[bb * 288 + i0 + tid] = 0.0f;

    if (IT == 0) {
        const int base = (p / 6) * 96 + (p % 6) * 16;
        for (int e = tid; e < 576; e += 128) {
            int il = e >> 4, j = e & 15;
            int i = i0 + il;
            int f = base + j;
            int h = f / 36, sp = f - h * 36;
            int y = sp / 6, x = sp - y * 6;
            int B = i / 9, kk = i - B * 9;
            int ki = kk / 3, kj = kk - ki * 3;
            float v = poses[(size_t)((bb * 512 + h * 32 + B) * 14 + 2 * x + ki) * 14 + 2 * y + kj];
            Pt_lds[e] = v;
            Ptg[pbase + (size_t)i0 * 16 + e] = v;
        }
        const int y = p / 6, x = p - y * 6;
        if (tid < 36) {
            int i = i0 + tid;
            int B = i / 9, kk = i - B * 9;
            int ki = kk / 3, kj = kk - ki * 3;
            float v = acts[(size_t)((bb * 32 + B) * 14 + 2 * x + ki) * 14 + 2 * y + kj];
            act_lds[tid] = v;
            actp[blk * 288 + i] = v;
        }
    } else {
        const float4* src = (const float4*)(Ptg + pbase + (size_t)i0 * 16);
        float4* dst = (float4*)Pt_lds;
        for (int e = tid; e < 144; e += 128) dst[e] = src[e];
        if (tid < 36) {
            act_lds[tid]  = actp[blk * 288 + i0 + tid];
            invd_lds[tid] = 1.0f / (denom_prev[bb * 288 + i0 + tid] + EPS);
        }
    }
    __syncthreads();

    f32x2 s1a01 = {0,0}, s1a23 = {0,0}, s2a01 = {0,0}, s2a23 = {0,0};
    f32x2 s1b01 = {0,0}, s1b23 = {0,0}, s2b01 = {0,0}, s2b23 = {0,0};
    float sRa = 0.f, sRb = 0.f;

    const float* Wt  = W + (size_t)iw * 512 + (lane << 2);
    const float* apc = ap_buf + apbase + (size_t)iw * 32 + cl;

#pragma unroll 6
    for (int t = 0; t < 18; ++t) {
        const int il = wave * 18 + t;
        const float4 wva = *(const float4*)(Wt + (size_t)t * 512);
        const float4 wvb = *(const float4*)(Wt + (size_t)t * 512 + 256);
        float Ra, Rb;
        if (IT == 0) {
            Ra = 1.0f / 32.0f; Rb = 1.0f / 32.0f;
        } else {
            const float inv = invd_lds[il];
            Ra = fmaf(apc[(size_t)t * 32],      inv, EPS);
            Rb = fmaf(apc[(size_t)t * 32 + 16], inv, EPS);
        }
        const float a_in = act_lds[il];
        const float R4a = Ra * a_in, R4b = Rb * a_in;
        sRa += R4a; sRb += R4b;

        const float4 q0 = *(const float4*)&Pt_lds[il * 16 + 0];
        const float4 q1 = *(const float4*)&Pt_lds[il * 16 + 4];
        const float4 q2 = *(const float4*)&Pt_lds[il * 16 + 8];
        const float4 q3 = *(const float4*)&Pt_lds[il * 16 + 12];

        f32x2 va01, va23, vb01, vb23;
        dot_pairs(wva, q0, q1, q2, q3, va01, va23);
        dot_pairs(wvb, q0, q1, q2, q3, vb01, vb23);

        const f32x2 ra2 = sp2(R4a), rb2 = sp2(R4b);
        s1a01 = fma2(ra2, va01, s1a01);
        s1a23 = fma2(ra2, va23, s1a23);
        s1b01 = fma2(rb2, vb01, s1b01);
        s1b23 = fma2(rb2, vb23, s1b23);
        const f32x2 ua01 = ra2 * va01, ua23 = ra2 * va23;
        const f32x2 ub01 = rb2 * vb01, ub23 = rb2 * vb23;
        s2a01 = fma2(ua01, va01, s2a01);
        s2a23 = fma2(ua23, va23, s2a23);
        s2b01 = fma2(ub01, vb01, s2b01);
        s2b23 = fma2(ub23, vb23, s2b23);
    }

    float acc[18] = {
        s1a01.x, s1a01.y, s1a23.x, s1a23.y,
        s2a01.x, s2a01.y, s2a23.x, s2a23.y,
        s1b01.x, s1b01.y, s1b23.x, s1b23.y,
        s2b01.x, s2b01.y, s2b23.x, s2b23.y,
        sRa, sRb
    };

    if (wave == 1) {
        float* d = &red[lane * 18];
#pragma unroll
        for (int k = 0; k < 18; ++k) d[k] = acc[k];
    }
    __syncthreads();
    if (wave == 0) {
        float* mp = Mpart + (size_t)bid * 1152;
        const float* r0 = &red[lane * 18];
#pragma unroll
        for (int k = 0; k < 18; ++k)
            mp[k * 64 + lane] = acc[k] + r0[k];
    }
}

// f_pass: reduce Mpart's 8 iq partials; FINAL=0: write packed PER-LANE
// Horner coefficients in place over Mpart[blk*9216]; FINAL=1: write d_out.
template <int FINAL>
__global__ __launch_bounds__(64)
void f_pass(float* __restrict__ Mpart, const float* __restrict__ beta_v,
            const float* __restrict__ beta_a, const float* __restrict__ lambda_p,
            float* __restrict__ d_out)
{
    const int lane = threadIdx.x;
    const int cl = lane >> 2, hr = lane & 3;
    const int blk = blockIdx.x;
    const int bb = blk / 36, p = blk - bb * 36;
    float* mp = Mpart + (size_t)blk * 9216;

    float s[18];
#pragma unroll
    for (int k = 0; k < 18; ++k) {
        float v = 0.f;
#pragma unroll
        for (int r = 0; r < 8; ++r)
            v += mp[(size_t)r * 1152 + k * 64 + lane];
        s[k] = v;
    }

    const float lam = lambda_p[0];
    float A2s[8], A1s[8], A0s[8], muv[8], av[2];
#pragma unroll
    for (int q = 0; q < 2; ++q) {
        const int c = cl + q * 16;
        const float sR = s[16 + q];
        float ls = 0.f;
#pragma unroll
        for (int hc = 0; hc < 4; ++hc) {
            const float mu = s[q * 8 + hc] / sR;
            float ss = s[q * 8 + 4 + hc] / sR - mu * mu;
            ss = fmaxf(ss, 1e-30f);
            const float n2 = (-0.5f / ss) * LOG2E;
            const float hl = (-0.5f * __logf(ss) - HALF_LN2PI) * LOG2E;
            muv[q * 4 + hc] = mu;
            A2s[q * 4 + hc] = n2;
            A1s[q * 4 + hc] = -2.0f * n2 * mu;
            A0s[q * 4 + hc] = fmaf(n2 * mu, mu, hl);
            ls += __logf(sqrtf(ss) + EPS);
        }
        ls += __shfl_xor(ls, 1);
        ls += __shfl_xor(ls, 2);
        const float cost = sR * (16.0f * beta_v[c] + ls);
        av[q] = 1.0f / (1.0f + __expf(-lam * (beta_a[c] - cost)));
    }

    if (FINAL) {
#pragma unroll
        for (int q = 0; q < 2; ++q) {
            const int c = cl + q * 16;
#pragma unroll
            for (int hc = 0; hc < 4; ++hc)
                d_out[(size_t)bb * 18432 + (size_t)(c * 36 + p) * 16 + hr * 4 + hc] = muv[q * 4 + hc];
            if (hr == 0)
                d_out[294912 + (size_t)bb * 1152 + c * 36 + p] = av[q];
        }
    } else {
        // in-place overwrite; single wave + fence orders reads before stores.
        asm volatile("s_waitcnt vmcnt(0)" ::: "memory");
#pragma unroll
        for (int q = 0; q < 2; ++q) {
#pragma unroll
            for (int hc = 0; hc < 4; ++hc) {
                const int ix = q * 256 + lane * 4 + hc;
                mp[ix]        = A2s[q * 4 + hc];
                mp[512 + ix]  = A1s[q * 4 + hc];
                mp[1024 + ix] = A0s[q * 4 + hc];
            }
            if (hr == 0) mp[1536 + q * 16 + cl] = av[q];
        }
    }
}

__global__ __launch_bounds__(128)
void e_pass(const float* __restrict__ Ptg, const float* __restrict__ Mpart,
            const float* __restrict__ W,
            float* __restrict__ ap_buf, float* __restrict__ denom_next)
{
    __shared__ __align__(16) float Pt_lds[576];
    __shared__ __align__(16) float ap_lds[1152];   // 36 i x 32 c

    const int tid  = threadIdx.x;
    const int wave = tid >> 6, lane = tid & 63;
    const int cl   = lane >> 2, hr = lane & 3;
    const int bid  = blockIdx.x;
    const int blk  = bid >> 3, iq = bid & 7;
    const int bb   = blk / 36;
    const int i0   = iq * 36;
    const int iw   = i0 + wave * 18;
    const size_t pbase  = (size_t)blk * 4608;
    const size_t apbase = (size_t)blk * 9216;

    {
        const float4* src = (const float4*)(Ptg + pbase + (size_t)i0 * 16);
        float4* dst = (float4*)Pt_lds;
        for (int e = tid; e < 144; e += 128) dst[e] = src[e];
    }

    // preamble: 6 float4 + 2 scalar loads of PER-LANE coefficients (r22)
    const float* st = Mpart + (size_t)blk * 9216;
    const float4 a2 = *(const float4*)&st[lane * 4];
    const float4 b2 = *(const float4*)&st[256 + lane * 4];
    const float4 a1 = *(const float4*)&st[512 + lane * 4];
    const float4 b1 = *(const float4*)&st[768 + lane * 4];
    const float4 a0 = *(const float4*)&st[1024 + lane * 4];
    const float4 b0 = *(const float4*)&st[1280 + lane * 4];
    const float aca = st[1536 + cl];
    const float acb = st[1552 + cl];

    f32x2 cA2a[2] = {f32x2{a2.x, a2.y}, f32x2{a2.z, a2.w}};
    f32x2 cA1a[2] = {f32x2{a1.x, a1.y}, f32x2{a1.z, a1.w}};
    f32x2 cA0a[2] = {f32x2{a0.x, a0.y}, f32x2{a0.z, a0.w}};
    f32x2 cA2b[2] = {f32x2{b2.x, b2.y}, f32x2{b2.z, b2.w}};
    f32x2 cA1b[2] = {f32x2{b1.x, b1.y}, f32x2{b1.z, b1.w}};
    f32x2 cA0b[2] = {f32x2{b0.x, b0.y}, f32x2{b0.z, b0.w}};
    __syncthreads();

    const float* Wt = W + (size_t)iw * 512 + (lane << 2);

#pragma unroll 6
    for (int t = 0; t < 18; ++t) {
        const int il = wave * 18 + t;
        const float4 wva = *(const float4*)(Wt + (size_t)t * 512);
        const float4 wvb = *(const float4*)(Wt + (size_t)t * 512 + 256);

        const float4 q0 = *(const float4*)&Pt_lds[il * 16 + 0];
        const float4 q1 = *(const float4*)&Pt_lds[il * 16 + 4];
        const float4 q2 = *(const float4*)&Pt_lds[il * 16 + 8];
        const float4 q3 = *(const float4*)&Pt_lds[il * 16 + 12];

        f32x2 va01, va23, vb01, vb23;
        dot_pairs(wva, q0, q1, q2, q3, va01, va23);
        dot_pairs(wvb, q0, q1, q2, q3, vb01, vb23);

        const f32x2 ga01 = fma2(va01, fma2(va01, cA2a[0], cA1a[0]), cA0a[0]);
        const f32x2 ga23 = fma2(va23, fma2(va23, cA2a[1], cA1a[1]), cA0a[1]);
        const f32x2 gb01 = fma2(vb01, fma2(vb01, cA2b[0], cA1b[0]), cA0b[0]);
        const f32x2 gb23 = fma2(vb23, fma2(vb23, cA2b[1], cA1b[1]), cA0b[1]);

        float pea = __builtin_amdgcn_exp2f(ga01.x) + __builtin_amdgcn_exp2f(ga01.y)
                  + __builtin_amdgcn_exp2f(ga23.x) + __builtin_amdgcn_exp2f(ga23.y);
        float peb = __builtin_amdgcn_exp2f(gb01.x) + __builtin_amdgcn_exp2f(gb01.y)
                  + __builtin_amdgcn_exp2f(gb23.x) + __builtin_amdgcn_exp2f(gb23.y);

        pea = qxor1_add(pea); pea = qxor2_add(pea);
        peb = qxor1_add(peb); peb = qxor2_add(peb);
        if (hr == 0) {
            ap_lds[il * 32 + cl]      = aca * pea;
            ap_lds[il * 32 + cl + 16] = acb * peb;
        }
    }
    __syncthreads();

    {
        const float4* s4 = (const float4*)ap_lds;
        float4* d4 = (float4*)(ap_buf + apbase + (size_t)i0 * 32);
        for (int e = tid; e < 288; e += 128) d4[e] = s4[e];
    }
    if (tid < 36) {
        float s = 0.f;
#pragma unroll
        for (int c = 0; c < 32; ++c)
            s += ap_lds[tid * 32 + ((c + tid) & 31)];   // bank-rotated
        atomicAdd(&denom_next[bb * 288 + i0 + tid], s);
    }
}

extern "C" void kernel_launch(void* const* d_in, const int* in_sizes, int n_in,
                              void* d_out, int out_size, void* d_ws, size_t ws_size,
                              hipStream_t stream)
{
    const float* lambda_p = (const float*)d_in[0];
    const float* poses    = (const float*)d_in[1];
    const float* acts     = (const float*)d_in[2];
    const float* W        = (const float*)d_in[3];
    const float* beta_v   = (const float*)d_in[4];
    const float* beta_a   = (const float*)d_in[5];
    float* out = (float*)d_out;

    float* ws     = (float*)d_ws;
    float* Ptg    = ws;                     // 2,654,208 floats
    float* actp   = Ptg + 2654208;          //   165,888
    float* ap_buf = actp + 165888;          // 5,308,416
    float* Mpart  = ap_buf + 5308416;       // 4608*1152 = 5,308,416 (moments -> coeffs)
    float* denom0 = Mpart + 5308416;        // 4608
    float* denom1 = denom0 + 4608;          // 4608
    // total ~13.45M floats = 53.8 MB (<< ws poison size ~256 MB)

    m_pass<0><<<4608, 128, 0, stream>>>(poses, acts, Ptg, actp, W, ap_buf, denom1, Mpart, denom0);
    f_pass<0><<<576, 64, 0, stream>>>(Mpart, beta_v, beta_a, lambda_p, out);
    e_pass<<<4608, 128, 0, stream>>>(Ptg, Mpart, W, ap_buf, denom0);
    m_pass<1><<<4608, 128, 0, stream>>>(poses, acts, Ptg, actp, W, ap_buf, denom0, Mpart, denom1);
    f_pass<0><<<576, 64, 0, stream>>>(Mpart, beta_v, beta_a, lambda_p, out);
    e_pass<<<4608, 128, 0, stream>>>(Ptg, Mpart, W, ap_buf, denom1);
    m_pass<1><<<4608, 128, 0, stream>>>(poses, acts, Ptg, actp, W, ap_buf, denom1, Mpart, denom0);
    f_pass<1><<<576, 64, 0, stream>>>(Mpart, beta_v, beta_a, lambda_p, out);
}

// Round 24
// 155.442 us; speedup vs baseline: 1.1094x; 1.1094x over previous
//
#include <hip/hip_runtime.h>

#define EPS 1e-10f
#define HALF_LN2PI 0.91893853320467274f
#define LOG2E 1.4426950408889634f

// b=16, win=14, w=6, ww=36, B_T=32, K=3, Bkk=288 (=i), C_T=32, HH=16
// W flat: [i=288][c=32][hr=4][m=4]
// Pt per (bb,p) (natural layout): Pt[i*16 + e] = patchflat[base(p)+e],
//   e = m*4+hc, base(p)=(p/6)*96+(p%6)*16.
//
// Grid (m/e): 2304 blocks = (blk = bb*36+p)*4 + iq, 192 threads = 3 waves.
// Wave handles 24 i. 9 blocks/CU x 3 waves = 27 waves/CU. VGPR <=64.
// lane = cl*4+hr; thread covers c in {cl, cl+16}, 4 hc each.
// Mpart[bid][k*64+lane], k: [0..3]=S1a [4..7]=S2a [8..11]=S1b [12..15]=S2b [16]=sRa [17]=sRb
//
// Stats hoist: f_pass reduces the 4 iq partials and writes PACKED PER-LANE
// coefficients IN PLACE over Mpart[blk*4608 + ...]:
//   A2 at [q*256 + lane*4 + hc], A1 at +512, A0 at +1024, a at [1536 + q*16 + cl]
// (per-lane keeps the hr dimension). Single-wave f_pass + vmcnt(0) fence.
//
// Structure: m0 -> f0 -> e0 -> m1 -> f1 -> e1 -> m2 -> f<FINAL> (8 dispatches).
//
// FINAL KERNEL (r24 = r22 restored). Search summary over 23 rounds:
//  r6 coop grid.sync = device L2 flush (19x regression) -> dispatch boundaries
//     are the cheap coherence mechanism on MI355X.
//  r7 full-unroll spilled acc[18] -> 1.18 GB scratch (9x).
//  r8 in-loop global VMEM/atomics share vmcnt FIFO with loads -> LDS-stage.
//  r9 hipMemsetAsync = 43us fillBuffer dispatch -> zero in-kernel; DPP reduce.
//  r11/r12 ablation: output path FREE; cost = t-loop math + W stream.
//  r13 quantified exp-delta = dependency structure, not trans throughput.
//  r14/r15 scalar instr cuts null; r17/r18 packed FP32 cut VALUBusy 70->54,
//     time flat; r19 poly-exp regressed; r20 unroll null -> t-loop is a
//     latency/issue equilibrium immovable from inside the kernel.
//  r16 occupancy 18->27 waves/CU +7us; r23 27->32 (more blocks) regressed.
//  r21 coeff hoist dropped the hr dimension (absmax 2.9e-2); r22 per-lane fix
//     -> +7us. Plateau: 3xe(38) + 3xm(8) + 3xf(2) + gaps ~= 156us, bound by
//     the 5-pass W-stream recompute schedule the grid-wide EM normalizer forces.

typedef float f32x2 __attribute__((ext_vector_type(2)));

__device__ __forceinline__ f32x2 fma2(f32x2 a, f32x2 b, f32x2 c) {
    return __builtin_elementwise_fma(a, b, c);
}
__device__ __forceinline__ f32x2 sp2(float x) { return f32x2{x, x}; }

__device__ __forceinline__ void dot_pairs(const float4 wv,
                                          const float4 q0, const float4 q1,
                                          const float4 q2, const float4 q3,
                                          f32x2& out01, f32x2& out23)
{
    out01 = fma2(sp2(wv.x), f32x2{q0.x, q0.y},
            fma2(sp2(wv.y), f32x2{q1.x, q1.y},
            fma2(sp2(wv.z), f32x2{q2.x, q2.y}, sp2(wv.w) * f32x2{q3.x, q3.y})));
    out23 = fma2(sp2(wv.x), f32x2{q0.z, q0.w},
            fma2(sp2(wv.y), f32x2{q1.z, q1.w},
            fma2(sp2(wv.z), f32x2{q2.z, q2.w}, sp2(wv.w) * f32x2{q3.z, q3.w})));
}

__device__ __forceinline__ float qxor1_add(float x) {
    float r;
    asm("v_add_f32 %0, %1, %1 quad_perm:[1,0,3,2] row_mask:0xf bank_mask:0xf"
        : "=v"(r) : "v"(x));
    return r;
}
__device__ __forceinline__ float qxor2_add(float x) {
    float r;
    asm("v_add_f32 %0, %1, %1 quad_perm:[2,3,0,1] row_mask:0xf bank_mask:0xf"
        : "=v"(r) : "v"(x));
    return r;
}

template <int IT>
__global__ __launch_bounds__(192)
void m_pass(const float* __restrict__ poses, const float* __restrict__ acts,
            float* __restrict__ Ptg, float* __restrict__ actp,
            const float* __restrict__ W,
            const float* __restrict__ ap_buf, const float* __restrict__ denom_prev,
            float* __restrict__ Mpart, float* __restrict__ denom_zero)
{
    __shared__ __align__(16) float Pt_lds[1152];
    __shared__ float act_lds[72];
    __shared__ float invd_lds[72];
    __shared__ __align__(16) float red[2304];

    const int tid  = threadIdx.x;
    const int wave = tid / 64, lane = tid & 63;
    const int cl   = lane >> 2;
    const int bid  = blockIdx.x;
    const int blk  = bid >> 2, iq = bid & 3;
    const int bb   = blk / 36, p = blk - bb * 36;
    const int i0   = iq * 72;
    const int iw   = i0 + wave * 24;
    const size_t pbase  = (size_t)blk * 4608;
    const size_t apbase = (size_t)blk * 9216;

    if (tid < 72)
        denom_zero[bb * 288 + i0 + tid] = 0.0f;

    if (IT == 0) {
        const int base = (p / 6) * 96 + (p % 6) * 16;
        for (int e = tid; e < 1152; e += 192) {
            int il = e >> 4, j = e & 15;
            int i = i0 + il;
            int f = base + j;
            int h = f / 36, sp = f - h * 36;
            int y = sp / 6, x = sp - y * 6;
            int B = i / 9, kk = i - B * 9;
            int ki = kk / 3, kj = kk - ki * 3;
            float v = poses[(size_t)((bb * 512 + h * 32 + B) * 14 + 2 * x + ki) * 14 + 2 * y + kj];
            Pt_lds[e] = v;
            Ptg[pbase + (size_t)i0 * 16 + e] = v;
        }
        const int y = p / 6, x = p - y * 6;
        for (int e = tid; e < 72; e += 192) {
            int i = i0 + e;
            int B = i / 9, kk = i - B * 9;
            int ki = kk / 3, kj = kk - ki * 3;
            float v = acts[(size_t)((bb * 32 + B) * 14 + 2 * x + ki) * 14 + 2 * y + kj];
            act_lds[e] = v;
            actp[blk * 288 + i] = v;
        }
    } else {
        const float4* src = (const float4*)(Ptg + pbase + (size_t)i0 * 16);
        float4* dst = (float4*)Pt_lds;
        for (int e = tid; e < 288; e += 192) dst[e] = src[e];
        for (int e = tid; e < 72; e += 192) {
            act_lds[e]  = actp[blk * 288 + i0 + e];
            invd_lds[e] = 1.0f / (denom_prev[bb * 288 + i0 + e] + EPS);
        }
    }
    __syncthreads();

    f32x2 s1a01 = {0,0}, s1a23 = {0,0}, s2a01 = {0,0}, s2a23 = {0,0};
    f32x2 s1b01 = {0,0}, s1b23 = {0,0}, s2b01 = {0,0}, s2b23 = {0,0};
    float sRa = 0.f, sRb = 0.f;

    const float* Wt  = W + (size_t)iw * 512 + (lane << 2);
    const float* apc = ap_buf + apbase + (size_t)iw * 32 + cl;

#pragma unroll 6
    for (int t = 0; t < 24; ++t) {
        const int il = wave * 24 + t;
        const float4 wva = *(const float4*)(Wt + (size_t)t * 512);
        const float4 wvb = *(const float4*)(Wt + (size_t)t * 512 + 256);
        float Ra, Rb;
        if (IT == 0) {
            Ra = 1.0f / 32.0f; Rb = 1.0f / 32.0f;
        } else {
            const float inv = invd_lds[il];
            Ra = fmaf(apc[(size_t)t * 32],      inv, EPS);
            Rb = fmaf(apc[(size_t)t * 32 + 16], inv, EPS);
        }
        const float a_in = act_lds[il];
        const float R4a = Ra * a_in, R4b = Rb * a_in;
        sRa += R4a; sRb += R4b;

        const float4 q0 = *(const float4*)&Pt_lds[il * 16 + 0];
        const float4 q1 = *(const float4*)&Pt_lds[il * 16 + 4];
        const float4 q2 = *(const float4*)&Pt_lds[il * 16 + 8];
        const float4 q3 = *(const float4*)&Pt_lds[il * 16 + 12];

        f32x2 va01, va23, vb01, vb23;
        dot_pairs(wva, q0, q1, q2, q3, va01, va23);
        dot_pairs(wvb, q0, q1, q2, q3, vb01, vb23);

        const f32x2 ra2 = sp2(R4a), rb2 = sp2(R4b);
        s1a01 = fma2(ra2, va01, s1a01);
        s1a23 = fma2(ra2, va23, s1a23);
        s1b01 = fma2(rb2, vb01, s1b01);
        s1b23 = fma2(rb2, vb23, s1b23);
        const f32x2 ua01 = ra2 * va01, ua23 = ra2 * va23;
        const f32x2 ub01 = rb2 * vb01, ub23 = rb2 * vb23;
        s2a01 = fma2(ua01, va01, s2a01);
        s2a23 = fma2(ua23, va23, s2a23);
        s2b01 = fma2(ub01, vb01, s2b01);
        s2b23 = fma2(ub23, vb23, s2b23);
    }

    float acc[18] = {
        s1a01.x, s1a01.y, s1a23.x, s1a23.y,
        s2a01.x, s2a01.y, s2a23.x, s2a23.y,
        s1b01.x, s1b01.y, s1b23.x, s1b23.y,
        s2b01.x, s2b01.y, s2b23.x, s2b23.y,
        sRa, sRb
    };

    if (wave > 0) {
        float* d = &red[((wave - 1) * 64 + lane) * 18];
#pragma unroll
        for (int k = 0; k < 18; ++k) d[k] = acc[k];
    }
    __syncthreads();
    if (wave == 0) {
        float* mp = Mpart + (size_t)bid * 1152;
        const float* r0 = &red[lane * 18];
        const float* r1 = &red[(64 + lane) * 18];
#pragma unroll
        for (int k = 0; k < 18; ++k)
            mp[k * 64 + lane] = acc[k] + r0[k] + r1[k];
    }
}

// f_pass: reduce Mpart's 4 iq partials; FINAL=0: write packed PER-LANE
// Horner coefficients in place over Mpart[blk]; FINAL=1: write d_out.
template <int FINAL>
__global__ __launch_bounds__(64)
void f_pass(float* __restrict__ Mpart, const float* __restrict__ beta_v,
            const float* __restrict__ beta_a, const float* __restrict__ lambda_p,
            float* __restrict__ d_out)
{
    const int lane = threadIdx.x;
    const int cl = lane >> 2, hr = lane & 3;
    const int blk = blockIdx.x;
    const int bb = blk / 36, p = blk - bb * 36;
    float* mp = Mpart + (size_t)blk * 4608;

    float s[18];
#pragma unroll
    for (int k = 0; k < 18; ++k)
        s[k] = mp[k * 64 + lane] + mp[1152 + k * 64 + lane]
             + mp[2304 + k * 64 + lane] + mp[3456 + k * 64 + lane];

    const float lam = lambda_p[0];
    float A2s[8], A1s[8], A0s[8], muv[8], av[2];
#pragma unroll
    for (int q = 0; q < 2; ++q) {
        const int c = cl + q * 16;
        const float sR = s[16 + q];
        float ls = 0.f;
#pragma unroll
        for (int hc = 0; hc < 4; ++hc) {
            const float mu = s[q * 8 + hc] / sR;
            float ss = s[q * 8 + 4 + hc] / sR - mu * mu;
            ss = fmaxf(ss, 1e-30f);
            const float n2 = (-0.5f / ss) * LOG2E;
            const float hl = (-0.5f * __logf(ss) - HALF_LN2PI) * LOG2E;
            muv[q * 4 + hc] = mu;
            A2s[q * 4 + hc] = n2;
            A1s[q * 4 + hc] = -2.0f * n2 * mu;
            A0s[q * 4 + hc] = fmaf(n2 * mu, mu, hl);
            ls += __logf(sqrtf(ss) + EPS);
        }
        ls += __shfl_xor(ls, 1);
        ls += __shfl_xor(ls, 2);
        const float cost = sR * (16.0f * beta_v[c] + ls);
        av[q] = 1.0f / (1.0f + __expf(-lam * (beta_a[c] - cost)));
    }

    if (FINAL) {
#pragma unroll
        for (int q = 0; q < 2; ++q) {
            const int c = cl + q * 16;
#pragma unroll
            for (int hc = 0; hc < 4; ++hc)
                d_out[(size_t)bb * 18432 + (size_t)(c * 36 + p) * 16 + hr * 4 + hc] = muv[q * 4 + hc];
            if (hr == 0)
                d_out[294912 + (size_t)bb * 1152 + c * 36 + p] = av[q];
        }
    } else {
        // in-place overwrite of Mpart[blk]; single wave + fence orders all
        // reads before any store.
        asm volatile("s_waitcnt vmcnt(0)" ::: "memory");
#pragma unroll
        for (int q = 0; q < 2; ++q) {
#pragma unroll
            for (int hc = 0; hc < 4; ++hc) {
                const int ix = q * 256 + lane * 4 + hc;
                mp[ix]        = A2s[q * 4 + hc];
                mp[512 + ix]  = A1s[q * 4 + hc];
                mp[1024 + ix] = A0s[q * 4 + hc];
            }
            if (hr == 0) mp[1536 + q * 16 + cl] = av[q];
        }
    }
}

__global__ __launch_bounds__(192)
void e_pass(const float* __restrict__ Ptg, const float* __restrict__ Mpart,
            const float* __restrict__ W,
            float* __restrict__ ap_buf, float* __restrict__ denom_next)
{
    __shared__ __align__(16) float Pt_lds[1152];
    __shared__ __align__(16) float ap_lds[2304];

    const int tid  = threadIdx.x;
    const int wave = tid / 64, lane = tid & 63;
    const int cl   = lane >> 2, hr = lane & 3;
    const int bid  = blockIdx.x;
    const int blk  = bid >> 2, iq = bid & 3;
    const int bb   = blk / 36;
    const int i0   = iq * 72;
    const int iw   = i0 + wave * 24;
    const size_t pbase  = (size_t)blk * 4608;
    const size_t apbase = (size_t)blk * 9216;

    {
        const float4* src = (const float4*)(Ptg + pbase + (size_t)i0 * 16);
        float4* dst = (float4*)Pt_lds;
        for (int e = tid; e < 288; e += 192) dst[e] = src[e];
    }

    // preamble: 6 float4 + 2 scalar loads of PER-LANE coefficients
    const float* st = Mpart + (size_t)blk * 4608;
    const float4 a2 = *(const float4*)&st[lane * 4];
    const float4 b2 = *(const float4*)&st[256 + lane * 4];
    const float4 a1 = *(const float4*)&st[512 + lane * 4];
    const float4 b1 = *(const float4*)&st[768 + lane * 4];
    const float4 a0 = *(const float4*)&st[1024 + lane * 4];
    const float4 b0 = *(const float4*)&st[1280 + lane * 4];
    const float aca = st[1536 + cl];
    const float acb = st[1552 + cl];

    f32x2 cA2a[2] = {f32x2{a2.x, a2.y}, f32x2{a2.z, a2.w}};
    f32x2 cA1a[2] = {f32x2{a1.x, a1.y}, f32x2{a1.z, a1.w}};
    f32x2 cA0a[2] = {f32x2{a0.x, a0.y}, f32x2{a0.z, a0.w}};
    f32x2 cA2b[2] = {f32x2{b2.x, b2.y}, f32x2{b2.z, b2.w}};
    f32x2 cA1b[2] = {f32x2{b1.x, b1.y}, f32x2{b1.z, b1.w}};
    f32x2 cA0b[2] = {f32x2{b0.x, b0.y}, f32x2{b0.z, b0.w}};
    __syncthreads();

    const float* Wt = W + (size_t)iw * 512 + (lane << 2);

#pragma unroll 8
    for (int t = 0; t < 24; ++t) {
        const int il = wave * 24 + t;
        const float4 wva = *(const float4*)(Wt + (size_t)t * 512);
        const float4 wvb = *(const float4*)(Wt + (size_t)t * 512 + 256);

        const float4 q0 = *(const float4*)&Pt_lds[il * 16 + 0];
        const float4 q1 = *(const float4*)&Pt_lds[il * 16 + 4];
        const float4 q2 = *(const float4*)&Pt_lds[il * 16 + 8];
        const float4 q3 = *(const float4*)&Pt_lds[il * 16 + 12];

        f32x2 va01, va23, vb01, vb23;
        dot_pairs(wva, q0, q1, q2, q3, va01, va23);
        dot_pairs(wvb, q0, q1, q2, q3, vb01, vb23);

        const f32x2 ga01 = fma2(va01, fma2(va01, cA2a[0], cA1a[0]), cA0a[0]);
        const f32x2 ga23 = fma2(va23, fma2(va23, cA2a[1], cA1a[1]), cA0a[1]);
        const f32x2 gb01 = fma2(vb01, fma2(vb01, cA2b[0], cA1b[0]), cA0b[0]);
        const f32x2 gb23 = fma2(vb23, fma2(vb23, cA2b[1], cA1b[1]), cA0b[1]);

        float pea = __builtin_amdgcn_exp2f(ga01.x) + __builtin_amdgcn_exp2f(ga01.y)
                  + __builtin_amdgcn_exp2f(ga23.x) + __builtin_amdgcn_exp2f(ga23.y);
        float peb = __builtin_amdgcn_exp2f(gb01.x) + __builtin_amdgcn_exp2f(gb01.y)
                  + __builtin_amdgcn_exp2f(gb23.x) + __builtin_amdgcn_exp2f(gb23.y);

        pea = qxor1_add(pea); pea = qxor2_add(pea);
        peb = qxor1_add(peb); peb = qxor2_add(peb);
        if (hr == 0) {
            ap_lds[il * 32 + cl]      = aca * pea;
            ap_lds[il * 32 + cl + 16] = acb * peb;
        }
    }
    __syncthreads();

    {
        const float4* s4 = (const float4*)ap_lds;
        float4* d4 = (float4*)(ap_buf + apbase + (size_t)i0 * 32);
        for (int e = tid; e < 576; e += 192) d4[e] = s4[e];
    }
    if (tid < 72) {
        float s = 0.f;
#pragma unroll
        for (int c = 0; c < 32; ++c)
            s += ap_lds[tid * 32 + ((c + tid) & 31)];
        atomicAdd(&denom_next[bb * 288 + i0 + tid], s);
    }
}

extern "C" void kernel_launch(void* const* d_in, const int* in_sizes, int n_in,
                              void* d_out, int out_size, void* d_ws, size_t ws_size,
                              hipStream_t stream)
{
    const float* lambda_p = (const float*)d_in[0];
    const float* poses    = (const float*)d_in[1];
    const float* acts     = (const float*)d_in[2];
    const float* W        = (const float*)d_in[3];
    const float* beta_v   = (const float*)d_in[4];
    const float* beta_a   = (const float*)d_in[5];
    float* out = (float*)d_out;

    float* ws     = (float*)d_ws;
    float* Ptg    = ws;                     // 2,654,208 floats
    float* actp   = Ptg + 2654208;          //   165,888
    float* ap_buf = actp + 165888;          // 5,308,416
    float* Mpart  = ap_buf + 5308416;       // 2,654,208 (moments, then coeffs in place)
    float* denom0 = Mpart + 2654208;        // 4608
    float* denom1 = denom0 + 4608;          // 4608

    m_pass<0><<<2304, 192, 0, stream>>>(poses, acts, Ptg, actp, W, ap_buf, denom1, Mpart, denom0);
    f_pass<0><<<576, 64, 0, stream>>>(Mpart, beta_v, beta_a, lambda_p, out);
    e_pass<<<2304, 192, 0, stream>>>(Ptg, Mpart, W, ap_buf, denom0);
    m_pass<1><<<2304, 192, 0, stream>>>(poses, acts, Ptg, actp, W, ap_buf, denom0, Mpart, denom1);
    f_pass<0><<<576, 64, 0, stream>>>(Mpart, beta_v, beta_a, lambda_p, out);
    e_pass<<<2304, 192, 0, stream>>>(Ptg, Mpart, W, ap_buf, denom1);
    m_pass<1><<<2304, 192, 0, stream>>>(poses, acts, Ptg, actp, W, ap_buf, denom1, Mpart, denom0);
    f_pass<1><<<576, 64, 0, stream>>>(Mpart, beta_v, beta_a, lambda_p, out);
}